// Round 6
// baseline (270.362 us; speedup 1.0000x reference)
//
#include <hip/hip_runtime.h>

// MaskedSelfAttention: B=256, T=165, C=384, H=6, D=64
// prep: x->bf16, Wqkv^T/Wproj^T -> bf16 | GEMM1 (xb@WqkvT+b -> QKV bf16) |
// attn per (b,h) (mask == full attn except y[164]=v[164]) | GEMM2 -> out fp32

typedef __attribute__((ext_vector_type(8))) short s16x8;
typedef __attribute__((ext_vector_type(4))) short s16x4;
typedef __attribute__((ext_vector_type(4))) float f32x4;

__device__ __forceinline__ ushort f2b(float f) {
  union { float f; unsigned u; } v; v.f = f;
  unsigned u = v.u;
  return (ushort)((u + 0x7FFFu + ((u >> 16) & 1u)) >> 16);
}

__device__ __forceinline__ void gload_lds16(const ushort* g, ushort* l) {
  __builtin_amdgcn_global_load_lds((const __attribute__((address_space(1))) void*)g,
                                   (__attribute__((address_space(3))) void*)l, 16, 0, 0);
}

#if __has_builtin(__builtin_amdgcn_mfma_f32_16x16x16bf16_1k)
__device__ __forceinline__ f32x4 mfma16x16x16(s16x4 a, s16x4 b, f32x4 c) {
  return __builtin_amdgcn_mfma_f32_16x16x16bf16_1k(a, b, c, 0, 0, 0);
}
#else
__device__ __forceinline__ f32x4 mfma16x16x16(s16x4 a, s16x4 b, f32x4 c) {
  asm("v_mfma_f32_16x16x16_bf16 %0, %1, %2, %0" : "+v"(c) : "v"(a), "v"(b));
  return c;
}
#endif

#if __has_builtin(__builtin_amdgcn_exp2f)
#define EXP2F(x) __builtin_amdgcn_exp2f(x)
#else
#define EXP2F(x) __expf((x) * 0.6931471805599453f)
#endif

#if __has_builtin(__builtin_amdgcn_rcpf)
#define RCPF(x) __builtin_amdgcn_rcpf(x)
#else
#define RCPF(x) (1.0f / (x))
#endif

// ---------------- prep: x fp32->bf16; weights fp32 -> bf16 transposed [N][K] ---------
__global__ __launch_bounds__(256) void prep(const float* __restrict__ x,
                                            const float* __restrict__ wq,
                                            const float* __restrict__ wp,
                                            ushort* __restrict__ xb,
                                            ushort* __restrict__ wqT,
                                            ushort* __restrict__ wpT)
{
  const int stride = gridDim.x * 256;
  const int i0 = blockIdx.x * 256 + threadIdx.x;
  for (int i = i0; i < 4055040; i += stride) {          // 42240*384/4
    float4 v = ((const float4*)x)[i];
    ushort4 h = make_ushort4(f2b(v.x), f2b(v.y), f2b(v.z), f2b(v.w));
    ((ushort4*)xb)[i] = h;
  }
  for (int i = i0; i < 110592; i += stride) {           // 1152*96
    const int n = i / 96, k4 = (i % 96) * 4;
    ushort4 h = make_ushort4(f2b(wq[(size_t)(k4 + 0) * 1152 + n]),
                             f2b(wq[(size_t)(k4 + 1) * 1152 + n]),
                             f2b(wq[(size_t)(k4 + 2) * 1152 + n]),
                             f2b(wq[(size_t)(k4 + 3) * 1152 + n]));
    *(ushort4*)(wqT + (size_t)n * 384 + k4) = h;
  }
  for (int i = i0; i < 36864; i += stride) {            // 384*96
    const int n = i / 96, k4 = (i % 96) * 4;
    ushort4 h = make_ushort4(f2b(wp[(size_t)(k4 + 0) * 384 + n]),
                             f2b(wp[(size_t)(k4 + 1) * 384 + n]),
                             f2b(wp[(size_t)(k4 + 2) * 384 + n]),
                             f2b(wp[(size_t)(k4 + 3) * 384 + n]));
    *(ushort4*)(wpT + (size_t)n * 384 + k4) = h;
  }
}

// ---------------- GEMM: A[M][384] bf16 @ Bt[N][384] bf16 + bias -> Out ----------------
// 128x128 tile, 4 waves (2x2). 1D grid with bijective XCD-chunked swizzle (m204).
// Double-buffered LDS + counted vmcnt (T3-minimum recipe, m218 pattern).
template<int NB, int NOUT, bool OUT_F32>
__global__ __launch_bounds__(256) void gemm_bias(const ushort* __restrict__ A,
                                                 const ushort* __restrict__ Bt,
                                                 const float* __restrict__ bias,
                                                 void* __restrict__ Out)
{
  __shared__ __align__(16) ushort Asm[2][128][64];   // [buf][row][k]
  __shared__ __align__(16) ushort Bsm[2][128][64];   // [buf][col][k]
  const int tid  = threadIdx.x;
  const int lane = tid & 63;
  const int wave = tid >> 6;
  const int wr = wave >> 1, wc = wave & 1;

  // bijective XCD-chunked swizzle: same-A-panel blocks land on the same XCD
  const int nwg = gridDim.x;
  const int qch = nwg >> 3, rch = nwg & 7;
  const int xcd = blockIdx.x & 7, idx = blockIdx.x >> 3;
  const int nl = (xcd < rch) ? xcd * (qch + 1) + idx
                             : rch * (qch + 1) + (xcd - rch) * qch + idx;
  const int n0 = (nl % NB) * 128;
  const int m0 = (nl / NB) * 128;

  // staging: thread tid covers LDS row tid>>3, col8 (tid&7)*8; dst = base + tid*16B
  const ushort* Ag = A  + (size_t)(m0 + (tid >> 3)) * 384 + ((tid & 7) << 3);
  const ushort* Bg = Bt + (size_t)(n0 + (tid >> 3)) * 384 + ((tid & 7) << 3);

  f32x4 acc[4][4] = {};

#define STAGE(buf, k0)                                              \
  {                                                                 \
    ushort* at_ = (ushort*)Asm[buf] + tid * 8;                      \
    ushort* bt_ = (ushort*)Bsm[buf] + tid * 8;                      \
    _Pragma("unroll")                                               \
    for (int i = 0; i < 4; ++i) {                                   \
      gload_lds16(Ag + (k0) + i * 32 * 384, at_ + i * 2048);        \
      gload_lds16(Bg + (k0) + i * 32 * 384, bt_ + i * 2048);        \
    }                                                               \
  }

  STAGE(0, 0);
  #pragma unroll
  for (int t = 0; t < 6; ++t) {
    const int cur = t & 1;
    if (t < 5) {
      STAGE(cur ^ 1, (t + 1) * 64);
      asm volatile("s_waitcnt vmcnt(8)" ::: "memory");   // oldest 8 (this tile) done
    } else {
      asm volatile("s_waitcnt vmcnt(0)" ::: "memory");
    }
    __builtin_amdgcn_s_barrier();                        // tile ready for all waves
    #pragma unroll
    for (int ks = 0; ks < 2; ++ks) {
      const int kk = (ks << 5) + ((lane >> 4) << 3);
      s16x8 a[4], b[4];
      #pragma unroll
      for (int mi = 0; mi < 4; ++mi)
        a[mi] = *(const s16x8*)(&Asm[cur][(wr << 6) + (mi << 4) + (lane & 15)][kk]);
      #pragma unroll
      for (int ni = 0; ni < 4; ++ni)
        b[ni] = *(const s16x8*)(&Bsm[cur][(wc << 6) + (ni << 4) + (lane & 15)][kk]);
      #pragma unroll
      for (int mi = 0; mi < 4; ++mi) {
        #pragma unroll
        for (int ni = 0; ni < 4; ++ni)
          acc[mi][ni] = __builtin_amdgcn_mfma_f32_16x16x32_bf16(a[mi], b[ni], acc[mi][ni], 0, 0, 0);
      }
    }
    __builtin_amdgcn_s_barrier();                        // all waves done reading tile
  }
#undef STAGE

  // epilogue: C/D layout col=lane&15, row=(lane>>4)*4+r
  #pragma unroll
  for (int mi = 0; mi < 4; ++mi) {
    #pragma unroll
    for (int ni = 0; ni < 4; ++ni) {
      const int col = n0 + (wc << 6) + (ni << 4) + (lane & 15);
      const float bv = bias[col];
      #pragma unroll
      for (int r = 0; r < 4; ++r) {
        const int row = m0 + (wr << 6) + (mi << 4) + ((lane >> 4) << 2) + r;
        const float v = acc[mi][ni][r] + bv;
        if (OUT_F32) ((float*)Out)[(size_t)row * NOUT + col] = v;
        else         ((ushort*)Out)[(size_t)row * NOUT + col] = f2b(v);
      }
    }
  }
}

// ---------------- Attention per (b,h), swapped-operand, barrier-free main loop -------
// S^T = mfma16x16x32(A=K, B=Q): lane holds q = lane&15, keys ct*16 + 4*grp + r.
// That layout IS the B-fragment layout of mfma_f32_16x16x16_bf16, so P feeds PV
// directly from registers (2 cvt_pk per ct). Y^T = mfma16x16x16(A=Vt, B=P^T) keeps
// q = lane&15 and yields 4 consecutive d per acc -> packed 8B stores.
// LDS: only V^T, packed key-pairs per u32: Vt32[d][p] = V[2p][d] | V[2p+1][d]<<16.
// Row stride 85 (odd mod 32) -> PV reads ~conflict-free; keys >=165 zeroed.
__global__ __launch_bounds__(256, 4) void attn_kernel(const ushort* __restrict__ QKV,
                                                      ushort* __restrict__ Y)
{
  __shared__ uint Vt32[64][85];   // 21760 B
  const int bh = blockIdx.x;
  const int b = bh / 6, h = bh % 6;
  const int tid = threadIdx.x, lane = tid & 63, wave = tid >> 6;
  const int colv = lane & 15, grp = lane >> 4;
  const size_t base = (size_t)b * 165 * 1152 + (size_t)h * 64;
  const ushort* Vg = QKV + base + 768;

  // stage V transposed + key-pair packed (2-way bank pattern = free)
  for (int idx = tid; idx < 85 * 8; idx += 256) {
    const int tp = idx >> 3, d8 = (idx & 7) << 3;
    const int t0 = 2 * tp, t1 = t0 + 1;
    uint4 a  = *(const uint4*)(Vg + (size_t)(t0 > 164 ? 164 : t0) * 1152 + d8);
    uint4 bv = *(const uint4*)(Vg + (size_t)(t1 > 164 ? 164 : t1) * 1152 + d8);
    if (t0 > 164) a  = make_uint4(0, 0, 0, 0);
    if (t1 > 164) bv = make_uint4(0, 0, 0, 0);
    const ushort* au = (const ushort*)&a;
    const ushort* bu = (const ushort*)&bv;
    #pragma unroll
    for (int j = 0; j < 8; ++j)
      Vt32[d8 + j][tp] = (uint)au[j] | ((uint)bu[j] << 16);
  }
  __syncthreads();   // the only barrier

  for (int it = 0; it < 3; ++it) {
    const int qt = wave + (it << 2);
    if (qt >= 11) continue;
    const int qrow = qt * 16 + colv;
    const ushort* qp = QKV + base + (size_t)(qrow > 164 ? 164 : qrow) * 1152;
    const s16x8 qf0 = *(const s16x8*)(qp + (grp << 3));
    const s16x8 qf1 = *(const s16x8*)(qp + 32 + (grp << 3));

    // QK^T (swapped): K fragments straight from global (L2-resident)
    f32x4 s[11];
    #pragma unroll
    for (int ct = 0; ct < 11; ++ct) {
      const int kr = ct * 16 + colv;
      const ushort* kp = QKV + base + (size_t)(kr > 164 ? 164 : kr) * 1152 + 384;
      const s16x8 kf0 = *(const s16x8*)(kp + (grp << 3));
      const s16x8 kf1 = *(const s16x8*)(kp + 32 + (grp << 3));
      f32x4 a = {};
      a = __builtin_amdgcn_mfma_f32_16x16x32_bf16(kf0, qf0, a, 0, 0, 0);
      a = __builtin_amdgcn_mfma_f32_16x16x32_bf16(kf1, qf1, a, 0, 0, 0);
      s[ct] = a * 0.18033688011112042f;   // (1/8) * log2(e): softmax in exp2 domain
    }
    // mask invalid keys (only ct=10: key = 160 + 4*grp + r >= 165)
    #pragma unroll
    for (int r = 0; r < 4; ++r)
      if (4 * grp + r >= 5) s[10][r] = -1e30f;

    // row max: local tree + 2 shuffles (4 lanes share a q-row: lane, ^16, ^32)
    float m = -1e30f;
    #pragma unroll
    for (int ct = 0; ct < 11; ++ct)
      m = fmaxf(m, fmaxf(fmaxf(s[ct][0], s[ct][1]), fmaxf(s[ct][2], s[ct][3])));
    m = fmaxf(m, __shfl_xor(m, 16));
    m = fmaxf(m, __shfl_xor(m, 32));
    // exp2 + sum (4 independent accumulation chains)
    float sm0 = 0.f, sm1 = 0.f, sm2 = 0.f, sm3 = 0.f;
    #pragma unroll
    for (int ct = 0; ct < 11; ++ct) {
      const float p0 = EXP2F(s[ct][0] - m), p1 = EXP2F(s[ct][1] - m);
      const float p2 = EXP2F(s[ct][2] - m), p3 = EXP2F(s[ct][3] - m);
      s[ct][0] = p0; s[ct][1] = p1; s[ct][2] = p2; s[ct][3] = p3;
      sm0 += p0; sm1 += p1; sm2 += p2; sm3 += p3;
    }
    float sum = (sm0 + sm1) + (sm2 + sm3);
    sum += __shfl_xor(sum, 16);
    sum += __shfl_xor(sum, 32);
    const float inv = RCPF(sum);

    // pack P to bf16 B-fragments (in-register, no LDS round-trip)
    s16x4 pk[11];
    #pragma unroll
    for (int ct = 0; ct < 11; ++ct) {
      uint w0, w1;
      float p0 = s[ct][0] * inv, p1 = s[ct][1] * inv;
      float p2 = s[ct][2] * inv, p3 = s[ct][3] * inv;
      asm("v_cvt_pk_bf16_f32 %0, %1, %2" : "=v"(w0) : "v"(p0), "v"(p1));
      asm("v_cvt_pk_bf16_f32 %0, %1, %2" : "=v"(w1) : "v"(p2), "v"(p3));
      uint* pw = (uint*)&pk[ct];
      pw[0] = w0; pw[1] = w1;
    }

    // PV: Y^T[d][q] via K=16 MFMA; A = Vt fragment (2 u32 LDS reads), B = pk[ct]
    f32x4 ya[4] = {};
    #pragma unroll
    for (int ct = 0; ct < 11; ++ct) {
      const int kk2 = 8 * ct + 2 * grp;
      #pragma unroll
      for (int dt = 0; dt < 4; ++dt) {
        uint w0 = 0, w1 = 0;
        if (!(ct == 10 && grp >= 2)) {        // keys >=168: p==0, skip garbage V
          w0 = Vt32[dt * 16 + colv][kk2];
          w1 = Vt32[dt * 16 + colv][kk2 + 1];
        }
        s16x4 vb;
        uint* vw = (uint*)&vb;
        vw[0] = w0; vw[1] = w1;
        ya[dt] = mfma16x16x16(vb, pk[ct], ya[dt]);
      }
    }

    // store: lane owns q = colv, d = dt*16 + 4*grp + {0..3} -> packed 8B stores
    const int trow = qt * 16 + colv;
    if (trow <= 164) {
      ushort* yrow = Y + ((size_t)b * 165 + trow) * 384 + h * 64;
      if (trow == 164) {                      // masked row: y[164] = v[164]
        #pragma unroll
        for (int dt = 0; dt < 4; ++dt) {
          const int d0 = dt * 16 + (grp << 2);
          *(uint2*)(yrow + d0) = *(const uint2*)(Vg + (size_t)164 * 1152 + d0);
        }
      } else {
        #pragma unroll
        for (int dt = 0; dt < 4; ++dt) {
          uint w0, w1;
          asm("v_cvt_pk_bf16_f32 %0, %1, %2" : "=v"(w0) : "v"(ya[dt][0]), "v"(ya[dt][1]));
          asm("v_cvt_pk_bf16_f32 %0, %1, %2" : "=v"(w1) : "v"(ya[dt][2]), "v"(ya[dt][3]));
          const int d0 = dt * 16 + (grp << 2);
          *(uint2*)(yrow + d0) = make_uint2(w0, w1);
        }
      }
    }
  }
}

extern "C" void kernel_launch(void* const* d_in, const int* in_sizes, int n_in,
                              void* d_out, int out_size, void* d_ws, size_t ws_size,
                              hipStream_t stream) {
  const float* x      = (const float*)d_in[0];
  const float* w_qkv  = (const float*)d_in[1];
  const float* b_qkv  = (const float*)d_in[2];
  const float* w_proj = (const float*)d_in[3];
  const float* b_proj = (const float*)d_in[4];
  float* out = (float*)d_out;

  char* ws = (char*)d_ws;
  // ws layout (bytes): xb/y 32440320 | wqT 884736 | wpT 294912 | QKV 97320960  = 130.94 MB
  ushort* xb  = (ushort*)ws;                      // x bf16 [42240][384]; reused as Y after GEMM1
  ushort* wqT = (ushort*)(ws + 32440320);         // [1152][384]
  ushort* wpT = (ushort*)(ws + 33325056);         // [384][384]
  ushort* qkv = (ushort*)(ws + 33619968);         // [42240][1152]
  ushort* y   = xb;

  prep<<<1024, 256, 0, stream>>>(x, w_qkv, w_proj, xb, wqT, wpT);
  gemm_bias<9, 1152, false><<<2970, 256, 0, stream>>>(xb, wqT, b_qkv, qkv);
  attn_kernel<<<1536, 256, 0, stream>>>(qkv, y);
  gemm_bias<3, 384, true><<<990, 256, 0, stream>>>(y, wpT, b_proj, out);
}

// Round 14
// 260.510 us; speedup vs baseline: 1.0378x; 1.0378x over previous
//
#include <hip/hip_runtime.h>

// MaskedSelfAttention: B=256, T=165, C=384, H=6, D=64
// prep: x->bf16, Wqkv^T/Wproj^T -> bf16 | GEMM1 (xb@WqkvT+b -> QKV bf16) |
// attn per (b,h) (mask == full attn except y[164]=v[164]) | GEMM2 -> out fp32
// This is the measured-best round-3/4 kernel (261 us) + ONE delta: Ksm padded 64->72
// (144 B row stride kills the 16-way bank conflict on K fragment reads).

typedef __attribute__((ext_vector_type(8))) short s16x8;
typedef __attribute__((ext_vector_type(4))) float f32x4;

__device__ __forceinline__ ushort f2b(float f) {
  union { float f; unsigned u; } v; v.f = f;
  unsigned u = v.u;
  return (ushort)((u + 0x7FFFu + ((u >> 16) & 1u)) >> 16);
}

__device__ __forceinline__ void gload_lds16(const ushort* g, ushort* l) {
  __builtin_amdgcn_global_load_lds((const __attribute__((address_space(1))) void*)g,
                                   (__attribute__((address_space(3))) void*)l, 16, 0, 0);
}

// ---------------- prep: x fp32->bf16; weights fp32 -> bf16 transposed [N][K] ---------
__global__ __launch_bounds__(256) void prep(const float* __restrict__ x,
                                            const float* __restrict__ wq,
                                            const float* __restrict__ wp,
                                            ushort* __restrict__ xb,
                                            ushort* __restrict__ wqT,
                                            ushort* __restrict__ wpT)
{
  const int stride = gridDim.x * 256;
  const int i0 = blockIdx.x * 256 + threadIdx.x;
  for (int i = i0; i < 4055040; i += stride) {          // 42240*384/4
    float4 v = ((const float4*)x)[i];
    ushort4 h = make_ushort4(f2b(v.x), f2b(v.y), f2b(v.z), f2b(v.w));
    ((ushort4*)xb)[i] = h;
  }
  for (int i = i0; i < 110592; i += stride) {           // 1152*96
    const int n = i / 96, k4 = (i % 96) * 4;
    ushort4 h = make_ushort4(f2b(wq[(size_t)(k4 + 0) * 1152 + n]),
                             f2b(wq[(size_t)(k4 + 1) * 1152 + n]),
                             f2b(wq[(size_t)(k4 + 2) * 1152 + n]),
                             f2b(wq[(size_t)(k4 + 3) * 1152 + n]));
    *(ushort4*)(wqT + (size_t)n * 384 + k4) = h;
  }
  for (int i = i0; i < 36864; i += stride) {            // 384*96
    const int n = i / 96, k4 = (i % 96) * 4;
    ushort4 h = make_ushort4(f2b(wp[(size_t)(k4 + 0) * 384 + n]),
                             f2b(wp[(size_t)(k4 + 1) * 384 + n]),
                             f2b(wp[(size_t)(k4 + 2) * 384 + n]),
                             f2b(wp[(size_t)(k4 + 3) * 384 + n]));
    *(ushort4*)(wpT + (size_t)n * 384 + k4) = h;
  }
}

// ---------------- GEMM: A[M][384] bf16 @ Bt[N][384] bf16 + bias -> Out ----------------
// 128x128 tile, 4 waves (2x2). 1D grid with bijective XCD-chunked swizzle (m204).
// Double-buffered LDS + counted vmcnt (T3-minimum recipe, m218 pattern).
template<int NB, int NOUT, bool OUT_F32>
__global__ __launch_bounds__(256) void gemm_bias(const ushort* __restrict__ A,
                                                 const ushort* __restrict__ Bt,
                                                 const float* __restrict__ bias,
                                                 void* __restrict__ Out)
{
  __shared__ __align__(16) ushort Asm[2][128][64];   // [buf][row][k]
  __shared__ __align__(16) ushort Bsm[2][128][64];   // [buf][col][k]
  const int tid  = threadIdx.x;
  const int lane = tid & 63;
  const int wave = tid >> 6;
  const int wr = wave >> 1, wc = wave & 1;

  // bijective XCD-chunked swizzle: same-A-panel blocks land on the same XCD
  const int nwg = gridDim.x;
  const int qch = nwg >> 3, rch = nwg & 7;
  const int xcd = blockIdx.x & 7, idx = blockIdx.x >> 3;
  const int nl = (xcd < rch) ? xcd * (qch + 1) + idx
                             : rch * (qch + 1) + (xcd - rch) * qch + idx;
  const int n0 = (nl % NB) * 128;
  const int m0 = (nl / NB) * 128;

  // staging: thread tid covers LDS row tid>>3, col8 (tid&7)*8; dst = base + tid*16B
  const ushort* Ag = A  + (size_t)(m0 + (tid >> 3)) * 384 + ((tid & 7) << 3);
  const ushort* Bg = Bt + (size_t)(n0 + (tid >> 3)) * 384 + ((tid & 7) << 3);

  f32x4 acc[4][4] = {};

#define STAGE(buf, k0)                                              \
  {                                                                 \
    ushort* at_ = (ushort*)Asm[buf] + tid * 8;                      \
    ushort* bt_ = (ushort*)Bsm[buf] + tid * 8;                      \
    _Pragma("unroll")                                               \
    for (int i = 0; i < 4; ++i) {                                   \
      gload_lds16(Ag + (k0) + i * 32 * 384, at_ + i * 2048);        \
      gload_lds16(Bg + (k0) + i * 32 * 384, bt_ + i * 2048);        \
    }                                                               \
  }

  STAGE(0, 0);
  #pragma unroll
  for (int t = 0; t < 6; ++t) {
    const int cur = t & 1;
    if (t < 5) {
      STAGE(cur ^ 1, (t + 1) * 64);
      asm volatile("s_waitcnt vmcnt(8)" ::: "memory");   // oldest 8 (this tile) done
    } else {
      asm volatile("s_waitcnt vmcnt(0)" ::: "memory");
    }
    __builtin_amdgcn_s_barrier();                        // tile ready for all waves
    #pragma unroll
    for (int ks = 0; ks < 2; ++ks) {
      const int kk = (ks << 5) + ((lane >> 4) << 3);
      s16x8 a[4], b[4];
      #pragma unroll
      for (int mi = 0; mi < 4; ++mi)
        a[mi] = *(const s16x8*)(&Asm[cur][(wr << 6) + (mi << 4) + (lane & 15)][kk]);
      #pragma unroll
      for (int ni = 0; ni < 4; ++ni)
        b[ni] = *(const s16x8*)(&Bsm[cur][(wc << 6) + (ni << 4) + (lane & 15)][kk]);
      #pragma unroll
      for (int mi = 0; mi < 4; ++mi) {
        #pragma unroll
        for (int ni = 0; ni < 4; ++ni)
          acc[mi][ni] = __builtin_amdgcn_mfma_f32_16x16x32_bf16(a[mi], b[ni], acc[mi][ni], 0, 0, 0);
      }
    }
    __builtin_amdgcn_s_barrier();                        // all waves done reading tile
  }
#undef STAGE

  // epilogue: C/D layout col=lane&15, row=(lane>>4)*4+r
  #pragma unroll
  for (int mi = 0; mi < 4; ++mi) {
    #pragma unroll
    for (int ni = 0; ni < 4; ++ni) {
      const int col = n0 + (wc << 6) + (ni << 4) + (lane & 15);
      const float bv = bias[col];
      #pragma unroll
      for (int r = 0; r < 4; ++r) {
        const int row = m0 + (wr << 6) + (mi << 4) + ((lane >> 4) << 2) + r;
        const float v = acc[mi][ni][r] + bv;
        if (OUT_F32) ((float*)Out)[(size_t)row * NOUT + col] = v;
        else         ((ushort*)Out)[(size_t)row * NOUT + col] = f2b(v);
      }
    }
  }
}

// ---------------- Attention per (b,h) ----------------
// QKV layout: [B*T][1152] bf16, q at col h*64+d, k at +384, v at +768.
// Y layout: [B*T][384] bf16.
// Full (unmasked) softmax(QK^T/8)V for all rows; row 164 overridden with v[164].
// Measured-passing round-3/4 structure; ONLY change: Ksm row 64 -> 72 (pad).
__global__ __launch_bounds__(256) void attn_kernel(const ushort* __restrict__ QKV,
                                                   ushort* __restrict__ Y)
{
  __shared__ __align__(16) ushort Ksm[165][72];      // [key t][d] padded  23760 B
  __shared__ __align__(16) ushort Vtsm[64][168];     // [d][key t]         21504 B
  __shared__ __align__(16) ushort Psm[4][16][168];   // per-wave P tile    21504 B
  const int bh = blockIdx.x;
  const int b = bh / 6, h = bh % 6;
  const int tid = threadIdx.x, lane = tid & 63, wave = tid >> 6;
  const size_t base = (size_t)b * 165 * 1152 + (size_t)h * 64;

  // stage K
  for (int idx = tid; idx < 165 * 8; idx += 256) {
    const int t = idx >> 3, d8 = (idx & 7) << 3;
    *(uint4*)(&Ksm[t][d8]) = *(const uint4*)(QKV + base + (size_t)t * 1152 + 384 + d8);
  }
  // stage V transposed
  for (int idx = tid; idx < 165 * 8; idx += 256) {
    const int t = idx >> 3, d8 = (idx & 7) << 3;
    uint4 v = *(const uint4*)(QKV + base + (size_t)t * 1152 + 768 + d8);
    const ushort* pv = (const ushort*)&v;
    #pragma unroll
    for (int j = 0; j < 8; ++j) Vtsm[d8 + j][t] = pv[j];
  }
  // zero pad Vt cols 165..167
  for (int idx = tid; idx < 64 * 3; idx += 256) Vtsm[idx / 3][165 + idx % 3] = 0;
  __syncthreads();

  const int colv = lane & 15;
  const int grp  = lane >> 4;
  for (int it = 0; it < 3; ++it) {
    const int qt = wave + (it << 2);
    const bool active = qt < 11;
    if (active) {
      const int tq = qt * 16 + colv;
      const int tqc = tq > 164 ? 164 : tq;
      const ushort* qrow = QKV + base + (size_t)tqc * 1152;
      const s16x8 qf0 = *(const s16x8*)(qrow + (grp << 3));
      const s16x8 qf1 = *(const s16x8*)(qrow + 32 + (grp << 3));
      f32x4 s[11];
      #pragma unroll
      for (int ct = 0; ct < 11; ++ct) {
        const int col = ct * 16 + colv;
        s16x8 kb0 = {}, kb1 = {};
        if (col < 165) {
          kb0 = *(const s16x8*)(&Ksm[col][grp << 3]);
          kb1 = *(const s16x8*)(&Ksm[col][32 + (grp << 3)]);
        }
        f32x4 a = {};
        a = __builtin_amdgcn_mfma_f32_16x16x32_bf16(qf0, kb0, a, 0, 0, 0);
        a = __builtin_amdgcn_mfma_f32_16x16x32_bf16(qf1, kb1, a, 0, 0, 0);
        s[ct] = a * 0.125f;
      }
      #pragma unroll
      for (int r = 0; r < 4; ++r) {
        float m = -1e30f;
        #pragma unroll
        for (int ct = 0; ct < 11; ++ct)
          if (ct * 16 + colv < 165) m = fmaxf(m, s[ct][r]);
        #pragma unroll
        for (int off = 1; off < 16; off <<= 1) m = fmaxf(m, __shfl_xor(m, off));
        float sum = 0.f;
        #pragma unroll
        for (int ct = 0; ct < 11; ++ct) {
          const float p = (ct * 16 + colv < 165) ? __expf(s[ct][r] - m) : 0.f;
          s[ct][r] = p;
          sum += p;
        }
        #pragma unroll
        for (int off = 1; off < 16; off <<= 1) sum += __shfl_xor(sum, off);
        const float inv = 1.f / sum;
        #pragma unroll
        for (int ct = 0; ct < 11; ++ct) s[ct][r] *= inv;
      }
      #pragma unroll
      for (int ct = 0; ct < 11; ++ct) {
        const int col = ct * 16 + colv;
        if (col < 168) {
          #pragma unroll
          for (int r = 0; r < 4; ++r)
            Psm[wave][(grp << 2) + r][col] = f2b(s[ct][r]);
        }
      }
    }
    __syncthreads();
    if (active) {
      f32x4 ya[4] = {};
      #pragma unroll
      for (int ksv = 0; ksv < 6; ++ksv) {
        const int kk = (ksv << 5) + (grp << 3);
        s16x8 pa = {};
        if (kk <= 160) pa = *(const s16x8*)(&Psm[wave][colv][kk]);
        #pragma unroll
        for (int nt = 0; nt < 4; ++nt) {
          s16x8 vb = {};
          if (kk <= 160) vb = *(const s16x8*)(&Vtsm[nt * 16 + colv][kk]);
          ya[nt] = __builtin_amdgcn_mfma_f32_16x16x32_bf16(pa, vb, ya[nt], 0, 0, 0);
        }
      }
      #pragma unroll
      for (int nt = 0; nt < 4; ++nt) {
        #pragma unroll
        for (int r = 0; r < 4; ++r) {
          const int trow = qt * 16 + (grp << 2) + r;
          if (trow < 165) {
            const int d = nt * 16 + colv;
            ushort val;
            if (trow == 164) val = QKV[base + (size_t)164 * 1152 + 768 + d];
            else             val = f2b(ya[nt][r]);
            Y[((size_t)b * 165 + trow) * 384 + h * 64 + d] = val;
          }
        }
      }
    }
    __syncthreads();
  }
}

extern "C" void kernel_launch(void* const* d_in, const int* in_sizes, int n_in,
                              void* d_out, int out_size, void* d_ws, size_t ws_size,
                              hipStream_t stream) {
  const float* x      = (const float*)d_in[0];
  const float* w_qkv  = (const float*)d_in[1];
  const float* b_qkv  = (const float*)d_in[2];
  const float* w_proj = (const float*)d_in[3];
  const float* b_proj = (const float*)d_in[4];
  float* out = (float*)d_out;

  char* ws = (char*)d_ws;
  // ws layout (bytes): xb/y 32440320 | wqT 884736 | wpT 294912 | QKV 97320960  = 130.94 MB
  ushort* xb  = (ushort*)ws;                      // x bf16 [42240][384]; reused as Y after GEMM1
  ushort* wqT = (ushort*)(ws + 32440320);         // [1152][384]
  ushort* wpT = (ushort*)(ws + 33325056);         // [384][384]
  ushort* qkv = (ushort*)(ws + 33619968);         // [42240][1152]
  ushort* y   = xb;

  prep<<<1024, 256, 0, stream>>>(x, w_qkv, w_proj, xb, wqT, wpT);
  gemm_bias<9, 1152, false><<<2970, 256, 0, stream>>>(xb, wqT, b_qkv, qkv);
  attn_kernel<<<1536, 256, 0, stream>>>(qkv, y);
  gemm_bias<3, 384, true><<<990, 256, 0, stream>>>(y, wpT, b_proj, out);
}